// Round 9
// baseline (1047.538 us; speedup 1.0000x reference)
//
#include <hip/hip_runtime.h>

#define NNODES 200000
#define MPAD   200064   // NNODES rounded up to 128
#define NEDGES 400000
#define FIN    165
#define K1P    192      // FIN padded to 6 x 32
#define HID    512
#define NB     ((NNODES + 255) / 256)   // 782 scan blocks

typedef __bf16 bf16_t;
typedef __bf16 bf16x8 __attribute__((ext_vector_type(8)));
typedef float  f32x4  __attribute__((ext_vector_type(4)));
typedef unsigned short su16x8 __attribute__((ext_vector_type(8)));
typedef float f32x4u __attribute__((ext_vector_type(4), aligned(4)));

static __device__ __forceinline__ float bf2f(unsigned short u) {
    unsigned int x = ((unsigned int)u) << 16;
    return __builtin_bit_cast(float, x);
}
static __device__ __forceinline__ unsigned short f2bf(float f) {
    bf16_t h = (bf16_t)f;  // RNE
    return __builtin_bit_cast(unsigned short, h);
}
// async global->LDS, 16B per lane (dest = wave-uniform base + lane*16)
static __device__ __forceinline__ void gl_lds16(const void* g, void* l) {
    __builtin_amdgcn_global_load_lds(
        (const __attribute__((address_space(1))) unsigned int*)g,
        (__attribute__((address_space(3))) unsigned int*)l, 16, 0, 0);
}

// ---------------- degree histograms ----------------
__global__ void k_deg(const int* __restrict__ src, const int* __restrict__ dst,
                      int* __restrict__ deg, int* __restrict__ cnt, int E) {
    int e = blockIdx.x * 256 + threadIdx.x;
    if (e < E) {
        atomicAdd(&deg[src[e]], 1);
        atomicAdd(&cnt[dst[e]], 1);
    }
}

// ---------------- CSR build: 2-level exclusive scan ----------------
__global__ void k_scan1(int* __restrict__ cnt, int* __restrict__ btot, int n) {
    __shared__ int s[256];
    int i = blockIdx.x * 256 + threadIdx.x;
    int v = (i < n) ? cnt[i] : 0;
    s[threadIdx.x] = v;
    __syncthreads();
    #pragma unroll
    for (int off = 1; off < 256; off <<= 1) {
        int t = (threadIdx.x >= off) ? s[threadIdx.x - off] : 0;
        __syncthreads();
        s[threadIdx.x] += t;
        __syncthreads();
    }
    if (i < n) cnt[i] = s[threadIdx.x] - v;
    if (threadIdx.x == 255) btot[blockIdx.x] = s[255];
}

__global__ void k_scan2(int* __restrict__ btot, int nb) {
    __shared__ int s[1024];
    int i = threadIdx.x;
    int v = (i < nb) ? btot[i] : 0;
    s[i] = v;
    __syncthreads();
    #pragma unroll
    for (int off = 1; off < 1024; off <<= 1) {
        int t = (i >= off) ? s[i - off] : 0;
        __syncthreads();
        s[i] += t;
        __syncthreads();
    }
    if (i < nb) btot[i] = s[i] - v;
}

__global__ void k_scan3(int* __restrict__ cnt, const int* __restrict__ btot,
                        int* __restrict__ rowptr, int n, int E) {
    int i = blockIdx.x * 256 + threadIdx.x;
    if (i < n) {
        rowptr[i] = cnt[i] + btot[blockIdx.x];
        cnt[i] = 0;
    }
    if (i == 0) rowptr[n] = E;
}

__global__ void k_scatter(const int* __restrict__ src, const int* __restrict__ dst,
                          const int* __restrict__ rowptr, int* __restrict__ cur,
                          int* __restrict__ esrc, int E) {
    int e = blockIdx.x * 256 + threadIdx.x;
    if (e < E) {
        int d = dst[e];
        int pos = rowptr[d] + atomicAdd(&cur[d], 1);
        esrc[pos] = src[e];
    }
}

// ---------------- build k-tiled bf16 B panel: P[kt][q][n][j] = W[kt*32+q*8+j][n] -------
__global__ void k_buildP(const float* __restrict__ W, unsigned short* __restrict__ P,
                         int kp, int kfull) {
    int idx = blockIdx.x * 256 + threadIdx.x;
    if (idx >= kp * HID) return;
    int j  = idx & 7;
    int n  = (idx >> 3) & 511;
    int q  = (idx >> 12) & 3;
    int kt = idx >> 14;
    int k  = kt * 32 + q * 8 + j;
    P[idx] = (k < kfull) ? f2bf(W[(size_t)k * HID + n]) : (unsigned short)0;
}

// ---------------- x -> bf16 padded [MPAD x 192] ----------------
__global__ void k_xcvt(const float* __restrict__ x, unsigned short* __restrict__ xb) {
    long i = ((long)blockIdx.x * 256 + threadIdx.x) * 8;
    if (i >= (long)NNODES * K1P) return;
    int row = (int)(i / K1P), k = (int)(i % K1P);
    const float* xr = x + (size_t)row * FIN;
    __align__(16) unsigned short v[8];
    #pragma unroll
    for (int j = 0; j < 8; ++j)
        v[j] = (k + j < FIN) ? f2bf(xr[k + j]) : (unsigned short)0;
    *(su16x8*)&xb[i] = *(su16x8*)v;
}

// ---------------- k_gemms: 128x128-tile GEMM, n-split; dual-destination by sel bit ----
// grid = (4*npanels, MPAD/128). sel = bx>>2 picks {panel of P, dst, ostride, obase}.
// Single-buffered 16KB LDS, 4 waves, gload_lds staging, swapped-operand MFMA, 8B stores.
// All A rows up to MPAD must be readable (padded allocs).
template<int K, int LDA>
__global__ __launch_bounds__(256, 4)
void k_gemms(const unsigned short* __restrict__ A, const unsigned short* __restrict__ P,
             unsigned short* __restrict__ D0, unsigned short* __restrict__ D1,
             int os0, int os1, int ob0, int ob1) {
    constexpr int KT = K / 32;
    __shared__ unsigned short Al[128 * 32];     // 8 KB
    __shared__ unsigned short Bl[4 * 128 * 8];  // 8 KB

    const int t    = threadIdx.x;
    const int lane = t & 63;
    const int wv   = t >> 6;
    const int wm   = wv >> 1, wn = wv & 1;
    const int sel  = blockIdx.x >> 2;
    const int ncol = (blockIdx.x & 3) * 128;
    const int m0   = blockIdx.y * 128;
    const unsigned short* Pb = P + (size_t)sel * K * 512 + ncol * 8;
    unsigned short* D = sel ? D1 : D0;
    const int os = sel ? os1 : os0;
    const int oc = (sel ? ob1 : ob0) + ncol;

    const int arow = t >> 2, ach = t & 3;
    const unsigned short* Ab = A + (size_t)m0 * LDA;

    f32x4 acc[4][4];
    #pragma unroll
    for (int m = 0; m < 4; ++m)
        #pragma unroll
        for (int n = 0; n < 4; ++n)
            acc[m][n] = (f32x4){0.f, 0.f, 0.f, 0.f};

    for (int kt = 0; kt < KT; ++kt) {
        __syncthreads();   // all waves done reading previous tile
        #pragma unroll
        for (int i = 0; i < 2; ++i) {   // stage A: rows (t>>2)+i*64, source pre-swizzled
            int r = arow + i * 64;
            gl_lds16(Ab + (size_t)r * LDA + kt * 32 + (ach ^ ((r >> 1) & 3)) * 8,
                     &Al[t * 8 + i * 2048]);
        }
        #pragma unroll
        for (int i = 0; i < 2; ++i)     // stage B: wave wv -> q-plane wv, contiguous
            gl_lds16(Pb + (size_t)kt * 16384 + wv * 4096 + lane * 8 + i * 512,
                     &Bl[wv * 1024 + lane * 8 + i * 512]);
        __syncthreads();   // staged data visible

        bf16x8 af[4], bfr[4];
        const int kq = lane >> 4;
        #pragma unroll
        for (int m = 0; m < 4; ++m) {
            int r = wm * 64 + m * 16 + (lane & 15);
            af[m] = *(const bf16x8*)&Al[r * 32 + 8 * (kq ^ ((r >> 1) & 3))];
        }
        #pragma unroll
        for (int n = 0; n < 4; ++n) {
            int c = wn * 64 + n * 16 + (lane & 15);
            bfr[n] = *(const bf16x8*)&Bl[kq * 1024 + c * 8];
        }
        #pragma unroll
        for (int m = 0; m < 4; ++m)
            #pragma unroll
            for (int n = 0; n < 4; ++n)
                acc[m][n] = __builtin_amdgcn_mfma_f32_16x16x32_bf16(bfr[n], af[m], acc[m][n], 0, 0, 0);
    }

    // epilogue: lane holds C[r][cb..cb+3] -> 8B store per (m,n)
    #pragma unroll
    for (int m = 0; m < 4; ++m) {
        int r = m0 + wm * 64 + m * 16 + (lane & 15);
        #pragma unroll
        for (int n = 0; n < 4; ++n) {
            int cb = oc + wn * 64 + n * 16 + (lane >> 4) * 4;
            uint2 pk;
            pk.x = ((unsigned int)f2bf(acc[m][n][1]) << 16) | (unsigned int)f2bf(acc[m][n][0]);
            pk.y = ((unsigned int)f2bf(acc[m][n][3]) << 16) | (unsigned int)f2bf(acc[m][n][2]);
            *(uint2*)&D[(size_t)r * os + cb] = pk;
        }
    }
}

// ---------------- k_gemmw: full-width K=512 (proven) — fallback in-place U0 pass ------
__global__ __launch_bounds__(512, 1)
void k_gemmw(const unsigned short* __restrict__ A, const unsigned short* __restrict__ P,
             unsigned short* __restrict__ U, int ooff, int M) {
    constexpr int KT = HID / 32;
    __shared__ unsigned short Al[2][128 * 32];
    __shared__ unsigned short Bl[2][4][HID * 8];

    const int t    = threadIdx.x;
    const int lane = t & 63;
    const int wv   = t >> 6;
    const int wm   = wv >> 2, wn = wv & 3;
    const int m0   = blockIdx.x * 128;

    const int srow = t >> 2;
    const int gch  = ((t & 3) ^ ((srow >> 1) & 3)) * 8;
    const unsigned short* Ab = A + (size_t)(m0 + srow) * 1024 + gch;
    const bool rok = (m0 + srow) < M;
    const unsigned short* Pb = P + (size_t)t * 8;

    f32x4 acc[4][8];
    #pragma unroll
    for (int m = 0; m < 4; ++m)
        #pragma unroll
        for (int n = 0; n < 8; ++n)
            acc[m][n] = (f32x4){0.f, 0.f, 0.f, 0.f};

    if (rok) gl_lds16(Ab, &Al[0][t * 8]);
    #pragma unroll
    for (int q = 0; q < 4; ++q) gl_lds16(Pb + q * 4096, &Bl[0][q][t * 8]);
    __syncthreads();

    int cur = 0;
    for (int kt = 0; kt < KT; ++kt) {
        if (kt + 1 < KT) {
            if (rok) gl_lds16(Ab + (kt + 1) * 32, &Al[cur ^ 1][t * 8]);
            const unsigned short* Pn = Pb + (size_t)(kt + 1) * 16384;
            #pragma unroll
            for (int q = 0; q < 4; ++q)
                gl_lds16(Pn + q * 4096, &Bl[cur ^ 1][q][t * 8]);
        }
        bf16x8 af[4], bfr[8];
        #pragma unroll
        for (int m = 0; m < 4; ++m) {
            int r  = wm * 64 + m * 16 + (lane & 15);
            int kq = lane >> 4;
            af[m] = *(const bf16x8*)&Al[cur][r * 32 + 8 * (kq ^ ((r >> 1) & 3))];
        }
        #pragma unroll
        for (int n = 0; n < 8; ++n) {
            int c = wn * 128 + n * 16 + (lane & 15);
            bfr[n] = *(const bf16x8*)&Bl[cur][lane >> 4][c * 8];
        }
        #pragma unroll
        for (int m = 0; m < 4; ++m)
            #pragma unroll
            for (int n = 0; n < 8; ++n)
                acc[m][n] = __builtin_amdgcn_mfma_f32_16x16x32_bf16(bfr[n], af[m], acc[m][n], 0, 0, 0);
        __syncthreads();
        cur ^= 1;
    }

    #pragma unroll
    for (int m = 0; m < 4; ++m) {
        int r = m0 + wm * 64 + m * 16 + (lane & 15);
        if (r < M) {
            #pragma unroll
            for (int n = 0; n < 8; ++n) {
                int cb = ooff + wn * 128 + n * 16 + (lane >> 4) * 4;
                uint2 pk;
                pk.x = ((unsigned int)f2bf(acc[m][n][1]) << 16) | (unsigned int)f2bf(acc[m][n][0]);
                pk.y = ((unsigned int)f2bf(acc[m][n][3]) << 16) | (unsigned int)f2bf(acc[m][n][2]);
                *(uint2*)&U[(size_t)r * 1024 + cb] = pk;
            }
        }
    }
}

// ---------------- fallback GEMM0 (f32 A, reg-staged) ----------------
__global__ __launch_bounds__(512, 1)
void k_gemm0(const float* __restrict__ Aptr, const unsigned short* __restrict__ P,
             unsigned short* __restrict__ U, int ooff, int M) {
    constexpr int K  = K1P;
    constexpr int KT = K / 32;
    __shared__ unsigned short Al[128 * 32];
    __shared__ unsigned short Bpl[4][HID * 8];

    const int t    = threadIdx.x;
    const int lane = t & 63;
    const int wv   = t >> 6;
    const int wm   = wv >> 2, wn = wv & 3;
    const int m0   = blockIdx.x * 128;

    f32x4 acc[4][8];
    #pragma unroll
    for (int m = 0; m < 4; ++m)
        #pragma unroll
        for (int n = 0; n < 8; ++n)
            acc[m][n] = (f32x4){0.f, 0.f, 0.f, 0.f};

    const int srow = t >> 2, sch = t & 3;
    const bool rok = (m0 + srow) < M;

    for (int kt = 0; kt < KT; ++kt) {
        const int k0 = kt * 32;
        __syncthreads();
        {
            const int gk = k0 + sch * 8;
            su16x8 av;
            float f[8];
            const float* Ab = Aptr + (size_t)(m0 + srow) * FIN + gk;
            if (rok && gk + 8 <= FIN) {
                f32x4u lo = *(const f32x4u*)Ab;
                f32x4u hi = *(const f32x4u*)(Ab + 4);
                f[0]=lo.x; f[1]=lo.y; f[2]=lo.z; f[3]=lo.w;
                f[4]=hi.x; f[5]=hi.y; f[6]=hi.z; f[7]=hi.w;
            } else {
                #pragma unroll
                for (int j = 0; j < 8; ++j)
                    f[j] = (rok && gk + j < FIN) ? Ab[j] : 0.f;
            }
            #pragma unroll
            for (int j = 0; j < 8; ++j) av[j] = f2bf(f[j]);
            *(su16x8*)&Al[srow * 32 + 8 * (sch ^ ((srow >> 1) & 3))] = av;
        }
        {
            const unsigned short* Pb = P + (size_t)kt * 16384 + t * 8;
            #pragma unroll
            for (int q = 0; q < 4; ++q)
                *(su16x8*)&Bpl[q][t * 8] = *(const su16x8*)(Pb + q * 4096);
        }
        __syncthreads();
        bf16x8 af[4], bfr[8];
        #pragma unroll
        for (int m = 0; m < 4; ++m) {
            int r  = wm * 64 + m * 16 + (lane & 15);
            int kq = lane >> 4;
            af[m] = *(const bf16x8*)&Al[r * 32 + 8 * (kq ^ ((r >> 1) & 3))];
        }
        #pragma unroll
        for (int n = 0; n < 8; ++n) {
            int c = wn * 128 + n * 16 + (lane & 15);
            bfr[n] = *(const bf16x8*)&Bpl[lane >> 4][c * 8];
        }
        #pragma unroll
        for (int m = 0; m < 4; ++m)
            #pragma unroll
            for (int n = 0; n < 8; ++n)
                acc[m][n] = __builtin_amdgcn_mfma_f32_16x16x32_bf16(bfr[n], af[m], acc[m][n], 0, 0, 0);
    }

    #pragma unroll
    for (int m = 0; m < 4; ++m) {
        int r = m0 + wm * 64 + m * 16 + (lane & 15);
        if (r < M) {
            #pragma unroll
            for (int n = 0; n < 8; ++n) {
                int cb = ooff + wn * 128 + n * 16 + (lane >> 4) * 4;
                uint2 pk;
                pk.x = ((unsigned int)f2bf(acc[m][n][1]) << 16) | (unsigned int)f2bf(acc[m][n][0]);
                pk.y = ((unsigned int)f2bf(acc[m][n][3]) << 16) | (unsigned int)f2bf(acc[m][n][2]);
                *(uint2*)&U[(size_t)r * 1024 + cb] = pk;
            }
        }
    }
}

// ---------------- aggr: U0[d] += sum_e w_e * U1[src_e]; optional fused bias+relu -------
template<int RELU>
__global__ void k_aggr(unsigned short* U, const int* __restrict__ rowptr,
                       const int* __restrict__ esrc, const int* __restrict__ deg,
                       const float* __restrict__ bias, int M) {
    int wid  = (blockIdx.x * 256 + threadIdx.x) >> 6;
    int lane = threadIdx.x & 63;
    if (wid >= M) return;
    int e0 = rowptr[wid], e1 = rowptr[wid + 1];
    if (RELU == 0 && e0 == e1) return;

    unsigned short* u0 = U + (size_t)wid * 1024 + lane * 8;
    uint4 v0 = *(const uint4*)u0;
    unsigned int a0[4] = {v0.x, v0.y, v0.z, v0.w};
    float acc[8];
    #pragma unroll
    for (int i = 0; i < 4; ++i) {
        acc[2 * i]     = bf2f((unsigned short)(a0[i] & 0xffffu));
        acc[2 * i + 1] = bf2f((unsigned short)(a0[i] >> 16));
    }

    if (e0 < e1) {
        int dd = deg[wid];
        float dr = dd > 0 ? rsqrtf((float)dd) : 0.f;
        for (int e = e0; e < e1; ++e) {
            int s = esrc[e];
            float we = -dr * rsqrtf((float)deg[s]);
            const uint4 v = *(const uint4*)(U + (size_t)s * 1024 + 512 + lane * 8);
            unsigned int uu[4] = {v.x, v.y, v.z, v.w};
            #pragma unroll
            for (int i = 0; i < 4; ++i) {
                acc[2 * i]     += we * bf2f((unsigned short)(uu[i] & 0xffffu));
                acc[2 * i + 1] += we * bf2f((unsigned short)(uu[i] >> 16));
            }
        }
    }

    if (RELU) {
        float4 c0 = *(const float4*)(bias + lane * 8);
        float4 c1 = *(const float4*)(bias + lane * 8 + 4);
        float bb[8] = {c0.x,c0.y,c0.z,c0.w,c1.x,c1.y,c1.z,c1.w};
        #pragma unroll
        for (int i = 0; i < 8; ++i) {
            float f = acc[i] + bb[i];
            acc[i] = f > 0.f ? f : 0.f;
        }
    }
    uint4 w4;
    unsigned int* wo = (unsigned int*)&w4;
    #pragma unroll
    for (int i = 0; i < 4; ++i)
        wo[i] = ((unsigned int)f2bf(acc[2 * i + 1]) << 16) | (unsigned int)f2bf(acc[2 * i]);
    *(uint4*)u0 = w4;
}

// ---------------- fused aggr + final: out[d] = relu(base[d]+prop+b2) @ Wl + bl --------
// Pre-act base read from (hp, hstride); gather always from U1-half (stride 1024).
__global__ void k_aggrf(const unsigned short* __restrict__ hp, int hstride,
                        const unsigned short* __restrict__ U, const int* __restrict__ rowptr,
                        const int* __restrict__ esrc, const int* __restrict__ deg,
                        const float* __restrict__ b2, const float* __restrict__ Wl,
                        const float* __restrict__ bl, float* __restrict__ out, int M) {
    int wid  = (blockIdx.x * 256 + threadIdx.x) >> 6;
    int lane = threadIdx.x & 63;
    if (wid >= M) return;
    int e0 = rowptr[wid], e1 = rowptr[wid + 1];

    const uint4 v0 = *(const uint4*)(hp + (size_t)wid * hstride + lane * 8);
    unsigned int a0[4] = {v0.x, v0.y, v0.z, v0.w};
    float acc[8];
    #pragma unroll
    for (int i = 0; i < 4; ++i) {
        acc[2 * i]     = bf2f((unsigned short)(a0[i] & 0xffffu));
        acc[2 * i + 1] = bf2f((unsigned short)(a0[i] >> 16));
    }
    if (e0 < e1) {
        int dd = deg[wid];
        float dr = dd > 0 ? rsqrtf((float)dd) : 0.f;
        for (int e = e0; e < e1; ++e) {
            int s = esrc[e];
            float we = -dr * rsqrtf((float)deg[s]);
            const uint4 v = *(const uint4*)(U + (size_t)s * 1024 + 512 + lane * 8);
            unsigned int uu[4] = {v.x, v.y, v.z, v.w};
            #pragma unroll
            for (int i = 0; i < 4; ++i) {
                acc[2 * i]     += we * bf2f((unsigned short)(uu[i] & 0xffffu));
                acc[2 * i + 1] += we * bf2f((unsigned short)(uu[i] >> 16));
            }
        }
    }
    float4 c0 = *(const float4*)(b2 + lane * 8);
    float4 c1 = *(const float4*)(b2 + lane * 8 + 4);
    float bb[8] = {c0.x,c0.y,c0.z,c0.w,c1.x,c1.y,c1.z,c1.w};
    const float4* Wp = reinterpret_cast<const float4*>(Wl + lane * 16);
    float4 w0 = Wp[0], w1 = Wp[1], w2 = Wp[2], w3 = Wp[3];
    float wv[16] = {w0.x, w0.y, w0.z, w0.w, w1.x, w1.y, w1.z, w1.w,
                    w2.x, w2.y, w2.z, w2.w, w3.x, w3.y, w3.z, w3.w};
    float s0 = 0.f, s1 = 0.f;
    #pragma unroll
    for (int i = 0; i < 8; ++i) {
        float f = acc[i] + bb[i];
        f = f > 0.f ? f : 0.f;
        s0 += f * wv[2 * i];
        s1 += f * wv[2 * i + 1];
    }
    #pragma unroll
    for (int off = 32; off; off >>= 1) {
        s0 += __shfl_xor(s0, off, 64);
        s1 += __shfl_xor(s1, off, 64);
    }
    if (lane == 0) {
        out[2 * (size_t)wid]     = s0 + bl[0];
        out[2 * (size_t)wid + 1] = s1 + bl[1];
    }
}

// ---------------- fallback final (when esrc lives in d_out) ----------------
__global__ void k_final(const unsigned short* __restrict__ U, const float* __restrict__ b2,
                        const float* __restrict__ Wl, const float* __restrict__ bl,
                        float* __restrict__ out, int M) {
    int wid  = (blockIdx.x * 256 + threadIdx.x) >> 6;
    int lane = threadIdx.x & 63;
    if (wid >= M) return;
    const uint4 v = *(const uint4*)(U + (size_t)wid * 1024 + lane * 8);
    float4 c0 = *(const float4*)(b2 + lane * 8);
    float4 c1 = *(const float4*)(b2 + lane * 8 + 4);
    float bb[8] = {c0.x,c0.y,c0.z,c0.w,c1.x,c1.y,c1.z,c1.w};
    const float4* Wp = reinterpret_cast<const float4*>(Wl + lane * 16);
    float4 w0 = Wp[0], w1 = Wp[1], w2 = Wp[2], w3 = Wp[3];
    float wv[16] = {w0.x, w0.y, w0.z, w0.w, w1.x, w1.y, w1.z, w1.w,
                    w2.x, w2.y, w2.z, w2.w, w3.x, w3.y, w3.z, w3.w};
    unsigned int uu[4] = {v.x, v.y, v.z, v.w};
    float s0 = 0.f, s1 = 0.f;
    #pragma unroll
    for (int j = 0; j < 4; ++j) {
        float f0 = bf2f((unsigned short)(uu[j] & 0xffffu)) + bb[2 * j];
        float f1 = bf2f((unsigned short)(uu[j] >> 16))     + bb[2 * j + 1];
        f0 = f0 > 0.f ? f0 : 0.f;
        f1 = f1 > 0.f ? f1 : 0.f;
        s0 += f0 * wv[4 * j + 0];
        s1 += f0 * wv[4 * j + 1];
        s0 += f1 * wv[4 * j + 2];
        s1 += f1 * wv[4 * j + 3];
    }
    #pragma unroll
    for (int off = 32; off; off >>= 1) {
        s0 += __shfl_xor(s0, off, 64);
        s1 += __shfl_xor(s1, off, 64);
    }
    if (lane == 0) {
        out[2 * (size_t)wid]     = s0 + bl[0];
        out[2 * (size_t)wid + 1] = s1 + bl[1];
    }
}

extern "C" void kernel_launch(void* const* d_in, const int* in_sizes, int n_in,
                              void* d_out, int out_size, void* d_ws, size_t ws_size,
                              hipStream_t stream) {
    const float* x    = (const float*)d_in[0];
    const int*   ei   = (const int*)d_in[1];
    const float* W1_0 = (const float*)d_in[2];
    const float* W1_1 = (const float*)d_in[3];
    const float* b1   = (const float*)d_in[4];
    const float* W2_0 = (const float*)d_in[5];
    const float* W2_1 = (const float*)d_in[6];
    const float* b2   = (const float*)d_in[7];
    const float* Wl   = (const float*)d_in[8];
    const float* bl   = (const float*)d_in[9];
    const int* src = ei;
    const int* dst = ei + NEDGES;
    float* out = (float*)d_out;

    char* ws = (char*)d_ws;
    size_t off = 0;
    auto alloc = [&](size_t bytes) -> void* {
        void* p = ws + off;
        off += (bytes + 255) & ~(size_t)255;
        return p;
    };
    int*            deg    = (int*)alloc((size_t)NNODES * 4);
    int*            cnt    = (int*)alloc((size_t)NNODES * 4);
    int*            rowptr = (int*)alloc((size_t)(NNODES + 1) * 4);
    int*            btot   = (int*)alloc((size_t)NB * 4);
    unsigned short* P1     = (unsigned short*)alloc((size_t)2 * K1P * HID * 2);
    unsigned short* P2     = (unsigned short*)alloc((size_t)2 * HID * HID * 2);
    unsigned short* U      = (unsigned short*)alloc((size_t)MPAD * 1024 * 2);  // padded rows

    bool esrc_ws = (off + (size_t)NEDGES * 4 <= ws_size);
    int* esrc = esrc_ws ? (int*)alloc((size_t)NEDGES * 4) : (int*)d_out;
    bool have_xb = (off + (size_t)MPAD * K1P * 2 <= ws_size);
    unsigned short* xb = have_xb ? (unsigned short*)alloc((size_t)MPAD * K1P * 2) : nullptr;
    // V: out-of-place dst for layer-2 h1@W2_0 pass (enables n-split for both passes)
    bool have_V = (off + (size_t)MPAD * HID * 2 <= ws_size);
    unsigned short* V = have_V ? (unsigned short*)alloc((size_t)MPAD * HID * 2) : nullptr;

    hipMemsetAsync(deg, 0, (size_t)NNODES * 4, stream);
    hipMemsetAsync(cnt, 0, (size_t)NNODES * 4, stream);

    // CSR build + degrees
    k_deg    <<<(NEDGES + 255) / 256, 256, 0, stream>>>(src, dst, deg, cnt, NEDGES);
    k_scan1  <<<NB, 256, 0, stream>>>(cnt, btot, NNODES);
    k_scan2  <<<1, 1024, 0, stream>>>(btot, NB);
    k_scan3  <<<NB, 256, 0, stream>>>(cnt, btot, rowptr, NNODES, NEDGES);
    k_scatter<<<(NEDGES + 255) / 256, 256, 0, stream>>>(src, dst, rowptr, cnt, esrc, NEDGES);

    // k-tiled weight panels
    const int pg1 = (K1P * HID + 255) / 256, pg2 = (HID * HID + 255) / 256;
    k_buildP<<<pg1, 256, 0, stream>>>(W1_0, P1, K1P, FIN);
    k_buildP<<<pg1, 256, 0, stream>>>(W1_1, P1 + (size_t)K1P * HID, K1P, FIN);
    k_buildP<<<pg2, 256, 0, stream>>>(W2_0, P2, HID, HID);
    k_buildP<<<pg2, 256, 0, stream>>>(W2_1, P2 + (size_t)HID * HID, HID, HID);

    const int nblk = MPAD / 128;  // 1563

    // layer 1: U = x @ [W1_0|W1_1]  (both panels, one n-split dispatch)
    if (have_xb) {
        k_xcvt<<<(int)(((long)NNODES * K1P / 8 + 255) / 256), 256, 0, stream>>>(x, xb);
        k_gemms<K1P, K1P><<<dim3(8, nblk), 256, 0, stream>>>(xb, P1, U, U, 1024, 1024, 0, 512);
    } else {
        k_gemm0<<<nblk, 512, 0, stream>>>(x, P1, U, 0, NNODES);
        k_gemm0<<<nblk, 512, 0, stream>>>(x, P1 + (size_t)K1P * HID, U, 512, NNODES);
    }
    // aggr folds prop + bias + relu -> U0 = h1
    k_aggr<1><<<NNODES / 4, 256, 0, stream>>>(U, rowptr, esrc, deg, b1, NNODES);

    // layer 2
    if (have_V) {
        // one dispatch, both panels: sel=0 -> V = h1@W2_0 (stride 512);
        //                            sel=1 -> U1 = h1@W2_1. All blocks read U0 only.
        k_gemms<HID, 1024><<<dim3(8, nblk), 256, 0, stream>>>(U, P2, V, U, 512, 1024, 0, 512);
    } else {
        k_gemms<HID, 1024><<<dim3(4, nblk), 256, 0, stream>>>(U, P2 + (size_t)HID * HID,
                                                              U, U, 1024, 1024, 512, 512);
        k_gemmw<<<nblk, 512, 0, stream>>>(U, P2, U, 0, NNODES);  // in-place U0
    }

    // prop + bias + relu + final GEMV
    const unsigned short* hp = have_V ? V : U;
    const int hstride = have_V ? HID : 1024;
    if (esrc_ws) {
        k_aggrf<<<NNODES / 4, 256, 0, stream>>>(hp, hstride, U, rowptr, esrc, deg,
                                                b2, Wl, bl, out, NNODES);
    } else {
        k_aggr<0><<<NNODES / 4, 256, 0, stream>>>(U, rowptr, esrc, deg, nullptr, NNODES);
        k_final<<<NNODES / 4, 256, 0, stream>>>(U, b2, Wl, bl, out, NNODES);
    }
}

// Round 10
// 917.367 us; speedup vs baseline: 1.1419x; 1.1419x over previous
//
#include <hip/hip_runtime.h>

#define NNODES 200000
#define MPAD   200064   // NNODES rounded up to 128
#define NEDGES 400000
#define FIN    165
#define K1P    192      // FIN padded to 6 x 32
#define HID    512
#define NB     ((NNODES + 255) / 256)   // 782 scan blocks

typedef __bf16 bf16_t;
typedef __bf16 bf16x8 __attribute__((ext_vector_type(8)));
typedef float  f32x4  __attribute__((ext_vector_type(4)));
typedef unsigned short su16x8 __attribute__((ext_vector_type(8)));
typedef float f32x4u __attribute__((ext_vector_type(4), aligned(4)));

static __device__ __forceinline__ float bf2f(unsigned short u) {
    unsigned int x = ((unsigned int)u) << 16;
    return __builtin_bit_cast(float, x);
}
static __device__ __forceinline__ unsigned short f2bf(float f) {
    bf16_t h = (bf16_t)f;  // RNE
    return __builtin_bit_cast(unsigned short, h);
}
// async global->LDS, 16B per lane (dest = wave-uniform base + lane*16)
static __device__ __forceinline__ void gl_lds16(const void* g, void* l) {
    __builtin_amdgcn_global_load_lds(
        (const __attribute__((address_space(1))) unsigned int*)g,
        (__attribute__((address_space(3))) unsigned int*)l, 16, 0, 0);
}

// ---------------- degree histograms ----------------
__global__ void k_deg(const int* __restrict__ src, const int* __restrict__ dst,
                      int* __restrict__ deg, int* __restrict__ cnt, int E) {
    int e = blockIdx.x * 256 + threadIdx.x;
    if (e < E) {
        atomicAdd(&deg[src[e]], 1);
        atomicAdd(&cnt[dst[e]], 1);
    }
}

// ---------------- CSR build: 2-level exclusive scan ----------------
__global__ void k_scan1(int* __restrict__ cnt, int* __restrict__ btot, int n) {
    __shared__ int s[256];
    int i = blockIdx.x * 256 + threadIdx.x;
    int v = (i < n) ? cnt[i] : 0;
    s[threadIdx.x] = v;
    __syncthreads();
    #pragma unroll
    for (int off = 1; off < 256; off <<= 1) {
        int t = (threadIdx.x >= off) ? s[threadIdx.x - off] : 0;
        __syncthreads();
        s[threadIdx.x] += t;
        __syncthreads();
    }
    if (i < n) cnt[i] = s[threadIdx.x] - v;
    if (threadIdx.x == 255) btot[blockIdx.x] = s[255];
}

__global__ void k_scan2(int* __restrict__ btot, int nb) {
    __shared__ int s[1024];
    int i = threadIdx.x;
    int v = (i < nb) ? btot[i] : 0;
    s[i] = v;
    __syncthreads();
    #pragma unroll
    for (int off = 1; off < 1024; off <<= 1) {
        int t = (i >= off) ? s[i - off] : 0;
        __syncthreads();
        s[i] += t;
        __syncthreads();
    }
    if (i < nb) btot[i] = s[i] - v;
}

__global__ void k_scan3(int* __restrict__ cnt, const int* __restrict__ btot,
                        int* __restrict__ rowptr, int n, int E) {
    int i = blockIdx.x * 256 + threadIdx.x;
    if (i < n) {
        rowptr[i] = cnt[i] + btot[blockIdx.x];
        cnt[i] = 0;
    }
    if (i == 0) rowptr[n] = E;
}

__global__ void k_scatter(const int* __restrict__ src, const int* __restrict__ dst,
                          const int* __restrict__ rowptr, int* __restrict__ cur,
                          int* __restrict__ esrc, int E) {
    int e = blockIdx.x * 256 + threadIdx.x;
    if (e < E) {
        int d = dst[e];
        int pos = rowptr[d] + atomicAdd(&cur[d], 1);
        esrc[pos] = src[e];
    }
}

// ---------------- build k-tiled bf16 B panel: P[kt][q][n][j] = W[kt*32+q*8+j][n] -------
__global__ void k_buildP(const float* __restrict__ W, unsigned short* __restrict__ P,
                         int kp, int kfull) {
    int idx = blockIdx.x * 256 + threadIdx.x;
    if (idx >= kp * HID) return;
    int j  = idx & 7;
    int n  = (idx >> 3) & 511;
    int q  = (idx >> 12) & 3;
    int kt = idx >> 14;
    int k  = kt * 32 + q * 8 + j;
    P[idx] = (k < kfull) ? f2bf(W[(size_t)k * HID + n]) : (unsigned short)0;
}

// concat panel for layer 2: K=1024, k<512 -> W2_0[k][n], else W2_1[k-512][n]
__global__ void k_buildP2cat(const float* __restrict__ W0, const float* __restrict__ W1,
                             unsigned short* __restrict__ P) {
    int idx = blockIdx.x * 256 + threadIdx.x;   // 1024*512 elems
    if (idx >= 1024 * HID) return;
    int j  = idx & 7;
    int n  = (idx >> 3) & 511;
    int q  = (idx >> 12) & 3;
    int kt = idx >> 14;
    int k  = kt * 32 + q * 8 + j;
    float v = (k < HID) ? W0[(size_t)k * HID + n] : W1[(size_t)(k - HID) * HID + n];
    P[idx] = f2bf(v);
}

// ---------------- x -> bf16 padded [MPAD x 192] ----------------
__global__ void k_xcvt(const float* __restrict__ x, unsigned short* __restrict__ xb) {
    long i = ((long)blockIdx.x * 256 + threadIdx.x) * 8;
    if (i >= (long)NNODES * K1P) return;
    int row = (int)(i / K1P), k = (int)(i % K1P);
    const float* xr = x + (size_t)row * FIN;
    __align__(16) unsigned short v[8];
    #pragma unroll
    for (int j = 0; j < 8; ++j)
        v[j] = (k + j < FIN) ? f2bf(xr[k + j]) : (unsigned short)0;
    *(su16x8*)&xb[i] = *(su16x8*)v;
}

// ---------------- k_gemms: 128x128-tile GEMM, n-split; dual-destination by sel bit ----
template<int K, int LDA>
__global__ __launch_bounds__(256, 4)
void k_gemms(const unsigned short* __restrict__ A, const unsigned short* __restrict__ P,
             unsigned short* __restrict__ D0, unsigned short* __restrict__ D1,
             int os0, int os1, int ob0, int ob1) {
    constexpr int KT = K / 32;
    __shared__ unsigned short Al[128 * 32];     // 8 KB
    __shared__ unsigned short Bl[4 * 128 * 8];  // 8 KB

    const int t    = threadIdx.x;
    const int lane = t & 63;
    const int wv   = t >> 6;
    const int wm   = wv >> 1, wn = wv & 1;
    const int sel  = blockIdx.x >> 2;
    const int ncol = (blockIdx.x & 3) * 128;
    const int m0   = blockIdx.y * 128;
    const unsigned short* Pb = P + (size_t)sel * K * 512 + ncol * 8;
    unsigned short* D = sel ? D1 : D0;
    const int os = sel ? os1 : os0;
    const int oc = (sel ? ob1 : ob0) + ncol;

    const int arow = t >> 2, ach = t & 3;
    const unsigned short* Ab = A + (size_t)m0 * LDA;

    f32x4 acc[4][4];
    #pragma unroll
    for (int m = 0; m < 4; ++m)
        #pragma unroll
        for (int n = 0; n < 4; ++n)
            acc[m][n] = (f32x4){0.f, 0.f, 0.f, 0.f};

    for (int kt = 0; kt < KT; ++kt) {
        __syncthreads();
        #pragma unroll
        for (int i = 0; i < 2; ++i) {
            int r = arow + i * 64;
            gl_lds16(Ab + (size_t)r * LDA + kt * 32 + (ach ^ ((r >> 1) & 3)) * 8,
                     &Al[t * 8 + i * 2048]);
        }
        #pragma unroll
        for (int i = 0; i < 2; ++i)
            gl_lds16(Pb + (size_t)kt * 16384 + wv * 4096 + lane * 8 + i * 512,
                     &Bl[wv * 1024 + lane * 8 + i * 512]);
        __syncthreads();

        bf16x8 af[4], bfr[4];
        const int kq = lane >> 4;
        #pragma unroll
        for (int m = 0; m < 4; ++m) {
            int r = wm * 64 + m * 16 + (lane & 15);
            af[m] = *(const bf16x8*)&Al[r * 32 + 8 * (kq ^ ((r >> 1) & 3))];
        }
        #pragma unroll
        for (int n = 0; n < 4; ++n) {
            int c = wn * 64 + n * 16 + (lane & 15);
            bfr[n] = *(const bf16x8*)&Bl[kq * 1024 + c * 8];
        }
        #pragma unroll
        for (int m = 0; m < 4; ++m)
            #pragma unroll
            for (int n = 0; n < 4; ++n)
                acc[m][n] = __builtin_amdgcn_mfma_f32_16x16x32_bf16(bfr[n], af[m], acc[m][n], 0, 0, 0);
    }

    #pragma unroll
    for (int m = 0; m < 4; ++m) {
        int r = m0 + wm * 64 + m * 16 + (lane & 15);
        #pragma unroll
        for (int n = 0; n < 4; ++n) {
            int cb = oc + wn * 64 + n * 16 + (lane >> 4) * 4;
            uint2 pk;
            pk.x = ((unsigned int)f2bf(acc[m][n][1]) << 16) | (unsigned int)f2bf(acc[m][n][0]);
            pk.y = ((unsigned int)f2bf(acc[m][n][3]) << 16) | (unsigned int)f2bf(acc[m][n][2]);
            *(uint2*)&D[(size_t)r * os + cb] = pk;
        }
    }
}

// ---------------- k_gemmf: K=1024 concat GEMM + fused relu/bias + final Linear --------
// Z = [h1|prop(h1)] @ [W2_0;W2_1]; epilogue: out[r] += sum_c relu(Z+b2)*Wl (f32 atomics).
// out pre-initialized to bl by k_initout. h2pre never materializes.
__global__ __launch_bounds__(256, 4)
void k_gemmf(const unsigned short* __restrict__ A, const unsigned short* __restrict__ P,
             const float* __restrict__ b2, const float* __restrict__ Wl,
             float* __restrict__ out) {
    constexpr int K = 1024, LDA = 1024, KT = K / 32;
    __shared__ unsigned short Al[128 * 32];
    __shared__ unsigned short Bl[4 * 128 * 8];

    const int t    = threadIdx.x;
    const int lane = t & 63;
    const int wv   = t >> 6;
    const int wm   = wv >> 1, wn = wv & 1;
    const int ncol = blockIdx.x * 128;
    const int m0   = blockIdx.y * 128;
    const unsigned short* Pb = P + ncol * 8;
    const int arow = t >> 2, ach = t & 3;
    const unsigned short* Ab = A + (size_t)m0 * LDA;

    f32x4 acc[4][4];
    #pragma unroll
    for (int m = 0; m < 4; ++m)
        #pragma unroll
        for (int n = 0; n < 4; ++n)
            acc[m][n] = (f32x4){0.f, 0.f, 0.f, 0.f};

    for (int kt = 0; kt < KT; ++kt) {
        __syncthreads();
        #pragma unroll
        for (int i = 0; i < 2; ++i) {
            int r = arow + i * 64;
            gl_lds16(Ab + (size_t)r * LDA + kt * 32 + (ach ^ ((r >> 1) & 3)) * 8,
                     &Al[t * 8 + i * 2048]);
        }
        #pragma unroll
        for (int i = 0; i < 2; ++i)
            gl_lds16(Pb + (size_t)kt * 16384 + wv * 4096 + lane * 8 + i * 512,
                     &Bl[wv * 1024 + lane * 8 + i * 512]);
        __syncthreads();

        bf16x8 af[4], bfr[4];
        const int kq = lane >> 4;
        #pragma unroll
        for (int m = 0; m < 4; ++m) {
            int r = wm * 64 + m * 16 + (lane & 15);
            af[m] = *(const bf16x8*)&Al[r * 32 + 8 * (kq ^ ((r >> 1) & 3))];
        }
        #pragma unroll
        for (int n = 0; n < 4; ++n) {
            int c = wn * 64 + n * 16 + (lane & 15);
            bfr[n] = *(const bf16x8*)&Bl[kq * 1024 + c * 8];
        }
        #pragma unroll
        for (int m = 0; m < 4; ++m)
            #pragma unroll
            for (int n = 0; n < 4; ++n)
                acc[m][n] = __builtin_amdgcn_mfma_f32_16x16x32_bf16(bfr[n], af[m], acc[m][n], 0, 0, 0);
    }

    // fused epilogue: lane holds Z[r][cg..cg+3] per (m,n)
    float s0[4] = {0.f, 0.f, 0.f, 0.f}, s1[4] = {0.f, 0.f, 0.f, 0.f};
    #pragma unroll
    for (int n = 0; n < 4; ++n) {
        int cg = ncol + wn * 64 + n * 16 + (lane >> 4) * 4;
        float4 bb   = *(const float4*)(b2 + cg);
        float4 wl01 = *(const float4*)(Wl + (size_t)cg * 2);
        float4 wl23 = *(const float4*)(Wl + (size_t)cg * 2 + 4);
        float b2v[4] = {bb.x, bb.y, bb.z, bb.w};
        float w0v[4] = {wl01.x, wl01.z, wl23.x, wl23.z};
        float w1v[4] = {wl01.y, wl01.w, wl23.y, wl23.w};
        #pragma unroll
        for (int m = 0; m < 4; ++m)
            #pragma unroll
            for (int j = 0; j < 4; ++j) {
                float z = acc[m][n][j] + b2v[j];
                z = z > 0.f ? z : 0.f;
                s0[m] += z * w0v[j];
                s1[m] += z * w1v[j];
            }
    }
    #pragma unroll
    for (int m = 0; m < 4; ++m) {   // reduce over lane>>4 groups (same row, 4 col-quads)
        s0[m] += __shfl_xor(s0[m], 16, 64);
        s0[m] += __shfl_xor(s0[m], 32, 64);
        s1[m] += __shfl_xor(s1[m], 16, 64);
        s1[m] += __shfl_xor(s1[m], 32, 64);
    }
    if (lane < 16) {
        #pragma unroll
        for (int m = 0; m < 4; ++m) {
            int r = m0 + wm * 64 + m * 16 + lane;
            if (r < NNODES) {
                unsafeAtomicAdd(&out[2 * (size_t)r],     s0[m]);
                unsafeAtomicAdd(&out[2 * (size_t)r + 1], s1[m]);
            }
        }
    }
}

__global__ void k_initout(float* __restrict__ out, const float* __restrict__ bl, int M) {
    int i = blockIdx.x * 256 + threadIdx.x;
    if (i < 2 * M) out[i] = bl[i & 1];
}

// ---------------- k_gemmw / k_gemm0: fallback kernels (proven round-7/8) --------------
__global__ __launch_bounds__(512, 1)
void k_gemmw(const unsigned short* __restrict__ A, const unsigned short* __restrict__ P,
             unsigned short* __restrict__ U, int ooff, int M) {
    constexpr int KT = HID / 32;
    __shared__ unsigned short Al[2][128 * 32];
    __shared__ unsigned short Bl[2][4][HID * 8];

    const int t    = threadIdx.x;
    const int lane = t & 63;
    const int wv   = t >> 6;
    const int wm   = wv >> 2, wn = wv & 3;
    const int m0   = blockIdx.x * 128;

    const int srow = t >> 2;
    const int gch  = ((t & 3) ^ ((srow >> 1) & 3)) * 8;
    const unsigned short* Ab = A + (size_t)(m0 + srow) * 1024 + gch;
    const bool rok = (m0 + srow) < M;
    const unsigned short* Pb = P + (size_t)t * 8;

    f32x4 acc[4][8];
    #pragma unroll
    for (int m = 0; m < 4; ++m)
        #pragma unroll
        for (int n = 0; n < 8; ++n)
            acc[m][n] = (f32x4){0.f, 0.f, 0.f, 0.f};

    if (rok) gl_lds16(Ab, &Al[0][t * 8]);
    #pragma unroll
    for (int q = 0; q < 4; ++q) gl_lds16(Pb + q * 4096, &Bl[0][q][t * 8]);
    __syncthreads();

    int cur = 0;
    for (int kt = 0; kt < KT; ++kt) {
        if (kt + 1 < KT) {
            if (rok) gl_lds16(Ab + (kt + 1) * 32, &Al[cur ^ 1][t * 8]);
            const unsigned short* Pn = Pb + (size_t)(kt + 1) * 16384;
            #pragma unroll
            for (int q = 0; q < 4; ++q)
                gl_lds16(Pn + q * 4096, &Bl[cur ^ 1][q][t * 8]);
        }
        bf16x8 af[4], bfr[8];
        #pragma unroll
        for (int m = 0; m < 4; ++m) {
            int r  = wm * 64 + m * 16 + (lane & 15);
            int kq = lane >> 4;
            af[m] = *(const bf16x8*)&Al[cur][r * 32 + 8 * (kq ^ ((r >> 1) & 3))];
        }
        #pragma unroll
        for (int n = 0; n < 8; ++n) {
            int c = wn * 128 + n * 16 + (lane & 15);
            bfr[n] = *(const bf16x8*)&Bl[cur][lane >> 4][c * 8];
        }
        #pragma unroll
        for (int m = 0; m < 4; ++m)
            #pragma unroll
            for (int n = 0; n < 8; ++n)
                acc[m][n] = __builtin_amdgcn_mfma_f32_16x16x32_bf16(bfr[n], af[m], acc[m][n], 0, 0, 0);
        __syncthreads();
        cur ^= 1;
    }

    #pragma unroll
    for (int m = 0; m < 4; ++m) {
        int r = m0 + wm * 64 + m * 16 + (lane & 15);
        if (r < M) {
            #pragma unroll
            for (int n = 0; n < 8; ++n) {
                int cb = ooff + wn * 128 + n * 16 + (lane >> 4) * 4;
                uint2 pk;
                pk.x = ((unsigned int)f2bf(acc[m][n][1]) << 16) | (unsigned int)f2bf(acc[m][n][0]);
                pk.y = ((unsigned int)f2bf(acc[m][n][3]) << 16) | (unsigned int)f2bf(acc[m][n][2]);
                *(uint2*)&U[(size_t)r * 1024 + cb] = pk;
            }
        }
    }
}

__global__ __launch_bounds__(512, 1)
void k_gemm0(const float* __restrict__ Aptr, const unsigned short* __restrict__ P,
             unsigned short* __restrict__ U, int ooff, int M) {
    constexpr int K  = K1P;
    constexpr int KT = K / 32;
    __shared__ unsigned short Al[128 * 32];
    __shared__ unsigned short Bpl[4][HID * 8];

    const int t    = threadIdx.x;
    const int lane = t & 63;
    const int wv   = t >> 6;
    const int wm   = wv >> 2, wn = wv & 3;
    const int m0   = blockIdx.x * 128;

    f32x4 acc[4][8];
    #pragma unroll
    for (int m = 0; m < 4; ++m)
        #pragma unroll
        for (int n = 0; n < 8; ++n)
            acc[m][n] = (f32x4){0.f, 0.f, 0.f, 0.f};

    const int srow = t >> 2, sch = t & 3;
    const bool rok = (m0 + srow) < M;

    for (int kt = 0; kt < KT; ++kt) {
        const int k0 = kt * 32;
        __syncthreads();
        {
            const int gk = k0 + sch * 8;
            su16x8 av;
            float f[8];
            const float* Ab = Aptr + (size_t)(m0 + srow) * FIN + gk;
            if (rok && gk + 8 <= FIN) {
                f32x4u lo = *(const f32x4u*)Ab;
                f32x4u hi = *(const f32x4u*)(Ab + 4);
                f[0]=lo.x; f[1]=lo.y; f[2]=lo.z; f[3]=lo.w;
                f[4]=hi.x; f[5]=hi.y; f[6]=hi.z; f[7]=hi.w;
            } else {
                #pragma unroll
                for (int j = 0; j < 8; ++j)
                    f[j] = (rok && gk + j < FIN) ? Ab[j] : 0.f;
            }
            #pragma unroll
            for (int j = 0; j < 8; ++j) av[j] = f2bf(f[j]);
            *(su16x8*)&Al[srow * 32 + 8 * (sch ^ ((srow >> 1) & 3))] = av;
        }
        {
            const unsigned short* Pb = P + (size_t)kt * 16384 + t * 8;
            #pragma unroll
            for (int q = 0; q < 4; ++q)
                *(su16x8*)&Bpl[q][t * 8] = *(const su16x8*)(Pb + q * 4096);
        }
        __syncthreads();
        bf16x8 af[4], bfr[8];
        #pragma unroll
        for (int m = 0; m < 4; ++m) {
            int r  = wm * 64 + m * 16 + (lane & 15);
            int kq = lane >> 4;
            af[m] = *(const bf16x8*)&Al[r * 32 + 8 * (kq ^ ((r >> 1) & 3))];
        }
        #pragma unroll
        for (int n = 0; n < 8; ++n) {
            int c = wn * 128 + n * 16 + (lane & 15);
            bfr[n] = *(const bf16x8*)&Bpl[lane >> 4][c * 8];
        }
        #pragma unroll
        for (int m = 0; m < 4; ++m)
            #pragma unroll
            for (int n = 0; n < 8; ++n)
                acc[m][n] = __builtin_amdgcn_mfma_f32_16x16x32_bf16(bfr[n], af[m], acc[m][n], 0, 0, 0);
    }

    #pragma unroll
    for (int m = 0; m < 4; ++m) {
        int r = m0 + wm * 64 + m * 16 + (lane & 15);
        if (r < M) {
            #pragma unroll
            for (int n = 0; n < 8; ++n) {
                int cb = ooff + wn * 128 + n * 16 + (lane >> 4) * 4;
                uint2 pk;
                pk.x = ((unsigned int)f2bf(acc[m][n][1]) << 16) | (unsigned int)f2bf(acc[m][n][0]);
                pk.y = ((unsigned int)f2bf(acc[m][n][3]) << 16) | (unsigned int)f2bf(acc[m][n][2]);
                *(uint2*)&U[(size_t)r * 1024 + cb] = pk;
            }
        }
    }
}

// ---------------- aggr: U0[d] += sum_e w_e * U1[src_e]; optional fused bias+relu -------
template<int RELU>
__global__ void k_aggr(unsigned short* U, const int* __restrict__ rowptr,
                       const int* __restrict__ esrc, const int* __restrict__ deg,
                       const float* __restrict__ bias, int M) {
    int wid  = (blockIdx.x * 256 + threadIdx.x) >> 6;
    int lane = threadIdx.x & 63;
    if (wid >= M) return;
    int e0 = rowptr[wid], e1 = rowptr[wid + 1];
    if (RELU == 0 && e0 == e1) return;

    unsigned short* u0 = U + (size_t)wid * 1024 + lane * 8;
    uint4 v0 = *(const uint4*)u0;
    unsigned int a0[4] = {v0.x, v0.y, v0.z, v0.w};
    float acc[8];
    #pragma unroll
    for (int i = 0; i < 4; ++i) {
        acc[2 * i]     = bf2f((unsigned short)(a0[i] & 0xffffu));
        acc[2 * i + 1] = bf2f((unsigned short)(a0[i] >> 16));
    }

    if (e0 < e1) {
        int dd = deg[wid];
        float dr = dd > 0 ? rsqrtf((float)dd) : 0.f;
        for (int e = e0; e < e1; ++e) {
            int s = esrc[e];
            float we = -dr * rsqrtf((float)deg[s]);
            const uint4 v = *(const uint4*)(U + (size_t)s * 1024 + 512 + lane * 8);
            unsigned int uu[4] = {v.x, v.y, v.z, v.w};
            #pragma unroll
            for (int i = 0; i < 4; ++i) {
                acc[2 * i]     += we * bf2f((unsigned short)(uu[i] & 0xffffu));
                acc[2 * i + 1] += we * bf2f((unsigned short)(uu[i] >> 16));
            }
        }
    }

    if (RELU) {
        float4 c0 = *(const float4*)(bias + lane * 8);
        float4 c1 = *(const float4*)(bias + lane * 8 + 4);
        float bb[8] = {c0.x,c0.y,c0.z,c0.w,c1.x,c1.y,c1.z,c1.w};
        #pragma unroll
        for (int i = 0; i < 8; ++i) {
            float f = acc[i] + bb[i];
            acc[i] = f > 0.f ? f : 0.f;
        }
    }
    uint4 w4;
    unsigned int* wo = (unsigned int*)&w4;
    #pragma unroll
    for (int i = 0; i < 4; ++i)
        wo[i] = ((unsigned int)f2bf(acc[2 * i + 1]) << 16) | (unsigned int)f2bf(acc[2 * i]);
    *(uint4*)u0 = w4;
}

// ---------------- aggr2: U1[d] = sum_e w_e * h1[src_e]  (h1 = U0-half) ----------------
__global__ void k_aggr2(unsigned short* U, const int* __restrict__ rowptr,
                        const int* __restrict__ esrc, const int* __restrict__ deg, int M) {
    int wid  = (blockIdx.x * 256 + threadIdx.x) >> 6;
    int lane = threadIdx.x & 63;
    if (wid >= M) return;
    int e0 = rowptr[wid], e1 = rowptr[wid + 1];

    float acc[8] = {0.f, 0.f, 0.f, 0.f, 0.f, 0.f, 0.f, 0.f};
    if (e0 < e1) {
        int dd = deg[wid];
        float dr = dd > 0 ? rsqrtf((float)dd) : 0.f;
        for (int e = e0; e < e1; ++e) {
            int s = esrc[e];
            float we = -dr * rsqrtf((float)deg[s]);
            const uint4 v = *(const uint4*)(U + (size_t)s * 1024 + lane * 8);  // U0-half
            unsigned int uu[4] = {v.x, v.y, v.z, v.w};
            #pragma unroll
            for (int i = 0; i < 4; ++i) {
                acc[2 * i]     += we * bf2f((unsigned short)(uu[i] & 0xffffu));
                acc[2 * i + 1] += we * bf2f((unsigned short)(uu[i] >> 16));
            }
        }
    }
    uint4 w4;
    unsigned int* wo = (unsigned int*)&w4;
    #pragma unroll
    for (int i = 0; i < 4; ++i)
        wo[i] = ((unsigned int)f2bf(acc[2 * i + 1]) << 16) | (unsigned int)f2bf(acc[2 * i]);
    *(uint4*)(U + (size_t)wid * 1024 + 512 + lane * 8) = w4;  // U1-half
}

// ---------------- fallback final (esrc-in-d_out path) ----------------
__global__ void k_final(const unsigned short* __restrict__ U, const float* __restrict__ b2,
                        const float* __restrict__ Wl, const float* __restrict__ bl,
                        float* __restrict__ out, int M) {
    int wid  = (blockIdx.x * 256 + threadIdx.x) >> 6;
    int lane = threadIdx.x & 63;
    if (wid >= M) return;
    const uint4 v = *(const uint4*)(U + (size_t)wid * 1024 + lane * 8);
    float4 c0 = *(const float4*)(b2 + lane * 8);
    float4 c1 = *(const float4*)(b2 + lane * 8 + 4);
    float bb[8] = {c0.x,c0.y,c0.z,c0.w,c1.x,c1.y,c1.z,c1.w};
    const float4* Wp = reinterpret_cast<const float4*>(Wl + lane * 16);
    float4 w0 = Wp[0], w1 = Wp[1], w2 = Wp[2], w3 = Wp[3];
    float wv[16] = {w0.x, w0.y, w0.z, w0.w, w1.x, w1.y, w1.z, w1.w,
                    w2.x, w2.y, w2.z, w2.w, w3.x, w3.y, w3.z, w3.w};
    unsigned int uu[4] = {v.x, v.y, v.z, v.w};
    float s0 = 0.f, s1 = 0.f;
    #pragma unroll
    for (int j = 0; j < 4; ++j) {
        float f0 = bf2f((unsigned short)(uu[j] & 0xffffu)) + bb[2 * j];
        float f1 = bf2f((unsigned short)(uu[j] >> 16))     + bb[2 * j + 1];
        f0 = f0 > 0.f ? f0 : 0.f;
        f1 = f1 > 0.f ? f1 : 0.f;
        s0 += f0 * wv[4 * j + 0];
        s1 += f0 * wv[4 * j + 1];
        s0 += f1 * wv[4 * j + 2];
        s1 += f1 * wv[4 * j + 3];
    }
    #pragma unroll
    for (int off = 32; off; off >>= 1) {
        s0 += __shfl_xor(s0, off, 64);
        s1 += __shfl_xor(s1, off, 64);
    }
    if (lane == 0) {
        out[2 * (size_t)wid]     = s0 + bl[0];
        out[2 * (size_t)wid + 1] = s1 + bl[1];
    }
}

extern "C" void kernel_launch(void* const* d_in, const int* in_sizes, int n_in,
                              void* d_out, int out_size, void* d_ws, size_t ws_size,
                              hipStream_t stream) {
    const float* x    = (const float*)d_in[0];
    const int*   ei   = (const int*)d_in[1];
    const float* W1_0 = (const float*)d_in[2];
    const float* W1_1 = (const float*)d_in[3];
    const float* b1   = (const float*)d_in[4];
    const float* W2_0 = (const float*)d_in[5];
    const float* W2_1 = (const float*)d_in[6];
    const float* b2   = (const float*)d_in[7];
    const float* Wl   = (const float*)d_in[8];
    const float* bl   = (const float*)d_in[9];
    const int* src = ei;
    const int* dst = ei + NEDGES;
    float* out = (float*)d_out;

    char* ws = (char*)d_ws;
    size_t off = 0;
    auto alloc = [&](size_t bytes) -> void* {
        void* p = ws + off;
        off += (bytes + 255) & ~(size_t)255;
        return p;
    };
    int*            deg    = (int*)alloc((size_t)NNODES * 4);
    int*            cnt    = (int*)alloc((size_t)NNODES * 4);
    int*            rowptr = (int*)alloc((size_t)(NNODES + 1) * 4);
    int*            btot   = (int*)alloc((size_t)NB * 4);
    unsigned short* P1     = (unsigned short*)alloc((size_t)2 * K1P * HID * 2);
    unsigned short* P2     = (unsigned short*)alloc((size_t)2 * HID * HID * 2); // cat or 2 panels
    unsigned short* U      = (unsigned short*)alloc((size_t)MPAD * 1024 * 2);

    bool esrc_ws = (off + (size_t)NEDGES * 4 <= ws_size);
    int* esrc = esrc_ws ? (int*)alloc((size_t)NEDGES * 4) : (int*)d_out;
    bool have_xb = (off + (size_t)MPAD * K1P * 2 <= ws_size);
    unsigned short* xb = have_xb ? (unsigned short*)alloc((size_t)MPAD * K1P * 2) : nullptr;

    hipMemsetAsync(deg, 0, (size_t)NNODES * 4, stream);
    hipMemsetAsync(cnt, 0, (size_t)NNODES * 4, stream);

    // CSR build + degrees
    k_deg    <<<(NEDGES + 255) / 256, 256, 0, stream>>>(src, dst, deg, cnt, NEDGES);
    k_scan1  <<<NB, 256, 0, stream>>>(cnt, btot, NNODES);
    k_scan2  <<<1, 1024, 0, stream>>>(btot, NB);
    k_scan3  <<<NB, 256, 0, stream>>>(cnt, btot, rowptr, NNODES, NEDGES);
    k_scatter<<<(NEDGES + 255) / 256, 256, 0, stream>>>(src, dst, rowptr, cnt, esrc, NEDGES);

    // weight panels
    const int pg1 = (K1P * HID + 255) / 256, pg2 = (HID * HID + 255) / 256;
    k_buildP<<<pg1, 256, 0, stream>>>(W1_0, P1, K1P, FIN);
    k_buildP<<<pg1, 256, 0, stream>>>(W1_1, P1 + (size_t)K1P * HID, K1P, FIN);
    if (esrc_ws) {
        k_buildP2cat<<<(1024 * HID + 255) / 256, 256, 0, stream>>>(W2_0, W2_1, P2);
    } else {
        k_buildP<<<pg2, 256, 0, stream>>>(W2_0, P2, HID, HID);
        k_buildP<<<pg2, 256, 0, stream>>>(W2_1, P2 + (size_t)HID * HID, HID, HID);
    }

    const int nblk = MPAD / 128;  // 1563

    // layer 1: U = x @ [W1_0|W1_1]
    if (have_xb) {
        k_xcvt<<<(int)(((long)NNODES * K1P / 8 + 255) / 256), 256, 0, stream>>>(x, xb);
        k_gemms<K1P, K1P><<<dim3(8, nblk), 256, 0, stream>>>(xb, P1, U, U, 1024, 1024, 0, 512);
    } else {
        k_gemm0<<<nblk, 512, 0, stream>>>(x, P1, U, 0, NNODES);
        k_gemm0<<<nblk, 512, 0, stream>>>(x, P1 + (size_t)K1P * HID, U, 512, NNODES);
    }
    // U0 = relu(U0 + prop(U1) + b1) = h1
    k_aggr<1><<<NNODES / 4, 256, 0, stream>>>(U, rowptr, esrc, deg, b1, NNODES);

    if (esrc_ws) {
        // layer 2 + final, fused: U1 = prop(h1); out = relu([h1|U1]@[W2_0;W2_1]+b2)@Wl+bl
        k_aggr2<<<NNODES / 4, 256, 0, stream>>>(U, rowptr, esrc, deg, NNODES);
        k_initout<<<(2 * NNODES + 255) / 256, 256, 0, stream>>>(out, bl, NNODES);
        k_gemmf<<<dim3(4, nblk), 256, 0, stream>>>(U, P2, b2, Wl, out);
    } else {
        // fallback: materialized layer 2 (round-8 proven path)
        k_gemms<HID, 1024><<<dim3(4, nblk), 256, 0, stream>>>(U, P2 + (size_t)HID * HID,
                                                              U, U, 1024, 1024, 512, 512);
        k_gemmw<<<nblk, 512, 0, stream>>>(U, P2, U, 0, NNODES);
        k_aggr<0><<<NNODES / 4, 256, 0, stream>>>(U, rowptr, esrc, deg, nullptr, NNODES);
        k_final<<<NNODES / 4, 256, 0, stream>>>(U, b2, Wl, bl, out, NNODES);
    }
}